// Round 10
// baseline (260.185 us; speedup 1.0000x reference)
//
#include <hip/hip_runtime.h>
#include <math.h>

// AVWGCN: B=64, N=2048, C_IN=C_OUT=64, CHEB_K=3, EMBED=16
#define NN    2048
#define BATCH 64
#define CIN   64
#define COUT  64
#define EMB   16
#define JDIM  4096   // BATCH*CIN
#define WKI   192    // CHEB_K*CIN
#define TPAD  138    // epilogue transpose stride (kept; harmless)

typedef __bf16 bf16_t;
typedef __bf16 bf16x8 __attribute__((ext_vector_type(8)));
typedef float  f32x4  __attribute__((ext_vector_type(4)));

#define GLOAD16(gp, lp) __builtin_amdgcn_global_load_lds( \
    (const __attribute__((address_space(1))) void*)(gp),  \
    (__attribute__((address_space(3))) void*)(lp), 16, 0, 0)

static __device__ __forceinline__ unsigned short bfbits(float f) {
    return __builtin_bit_cast(unsigned short, (bf16_t)f);
}

// ---------------------------------------------------------------------------
// Fused prelude: [0,2048) support | [2048,4096) y0 | [4096,5632) wgen-v5.
// All three independent (disjoint outputs, read-only inputs) -> no races.
// support blocks are latency-bound -> wgen's write stream hides under them.
// LDS union: 6656 floats = 26.6 KB -> 6 blocks/CU.
// ---------------------------------------------------------------------------
__global__ __launch_bounds__(256) void prelude_kernel(
    const float* __restrict__ x,  const float* __restrict__ E,
    const float* __restrict__ wp, bf16_t* __restrict__ Y0,
    bf16_t* __restrict__ Sb,      bf16_t* __restrict__ Wt) {
    __shared__ float smem[6656];
    const int bid = blockIdx.x;
    const int tid = threadIdx.x;

    if (bid < 2048) {
        // ============ support: Sb[n,:] = softmax(relu(E[n]@E^T)) ===========
        float* vals = smem;
        float* red  = smem + 2048;
        const int n = bid;

        float en[EMB];
#pragma unroll
        for (int d = 0; d < EMB; ++d) en[d] = E[n * EMB + d];

        float lmax = -1e30f;
        for (int m = tid; m < NN; m += 256) {
            const float4* em = reinterpret_cast<const float4*>(E + m * EMB);
            float dot = 0.f;
#pragma unroll
            for (int q = 0; q < EMB / 4; ++q) {
                float4 v = em[q];
                dot += en[q*4+0]*v.x + en[q*4+1]*v.y + en[q*4+2]*v.z + en[q*4+3]*v.w;
            }
            float r = fmaxf(dot, 0.f);
            vals[m] = r;
            lmax = fmaxf(lmax, r);
        }
#pragma unroll
        for (int off = 32; off > 0; off >>= 1)
            lmax = fmaxf(lmax, __shfl_down(lmax, off, 64));
        if ((tid & 63) == 0) red[tid >> 6] = lmax;
        __syncthreads();
        const float gmax = fmaxf(fmaxf(red[0], red[1]), fmaxf(red[2], red[3]));
        __syncthreads();

        float lsum = 0.f;
        for (int m = tid; m < NN; m += 256) {
            float e = expf(vals[m] - gmax);
            vals[m] = e;
            lsum += e;
        }
#pragma unroll
        for (int off = 32; off > 0; off >>= 1)
            lsum += __shfl_down(lsum, off, 64);
        if ((tid & 63) == 0) red[tid >> 6] = lsum;
        __syncthreads();
        const float inv = 1.f / (red[0] + red[1] + red[2] + red[3]);

        for (int m = tid; m < NN; m += 256)
            Sb[(size_t)n * NN + m] = (bf16_t)(vals[m] * inv);
    } else if (bid < 4096) {
        // ============ y0: Y0[b*64+c][n] = x[b][n][c] =======================
        float (*tile)[65] = reinterpret_cast<float(*)[65]>(smem);
        const int yb = bid - 2048;
        const int n0 = (yb & 31) * 64, b = yb >> 5;
        const int c = tid & 63, nn0 = tid >> 6;
        const float* src = x + ((size_t)b * NN + n0) * CIN + c;
#pragma unroll
        for (int p = 0; p < 16; ++p) {
            int nn = nn0 + p * 4;
            tile[nn][c] = src[(size_t)nn * CIN];
        }
        __syncthreads();
        const int cc = tid >> 2, q = tid & 3;
        bf16_t* dst = Y0 + (size_t)(b * 64 + cc) * NN + n0 + q * 16;
#pragma unroll
        for (int s4 = 0; s4 < 4; ++s4) {
            ushort4 pk;
            pk.x = bfbits(tile[q * 16 + s4 * 4 + 0][cc]);
            pk.y = bfbits(tile[q * 16 + s4 * 4 + 1][cc]);
            pk.z = bfbits(tile[q * 16 + s4 * 4 + 2][cc]);
            pk.w = bfbits(tile[q * 16 + s4 * 4 + 3][cc]);
            *reinterpret_cast<ushort4*>(dst + s4 * 4) = pk;
        }
    } else {
        // =========== wgen v5: two-phase coalesced fp32 wp staging ==========
        float* wL = smem;                                      // 6144 floats
        float (*sE)[16] = reinterpret_cast<float(*)[16]>(smem + 6144);
        const int wb = bid - 4096;
        const int s  = wb % 24;                // oki slice (512 wide)
        const int n0 = (wb / 24) * 32;         // node chunk
        const int oki0 = s * 512 + 2 * tid;
        const int o = oki0 / WKI, r0 = oki0 % WKI;
        const int o_lo = (s * 512) / WKI;
        const int oo_sel = o - o_lo;
        const int col = min(o_lo + (tid & 3), 63);

        if (tid < 128) {
            const int node = tid >> 2, q = tid & 3;
            *reinterpret_cast<float4*>(&sE[node][q * 4]) =
                *reinterpret_cast<const float4*>(E + (size_t)(n0 + node) * EMB + q * 4);
        }

        float w[2][EMB];
#pragma unroll
        for (int ph = 0; ph < 2; ++ph) {
            {
                const int oo = tid & 3;
#pragma unroll
                for (int i = 0; i < 24; ++i) {
                    int drl = (tid >> 2) + i * 64;            // 0..1535
                    wL[drl * 4 + oo] = wp[(size_t)(ph * 1536 + drl) * 64 + col];
                }
            }
            __syncthreads();
#pragma unroll
            for (int dh = 0; dh < 8; ++dh) {
                w[0][ph * 8 + dh] = wL[(dh * WKI + r0) * 4 + oo_sel];
                w[1][ph * 8 + dh] = wL[(dh * WKI + r0 + 1) * 4 + oo_sel];
            }
            __syncthreads();   // protect wL before phase-2 overwrite
        }

#pragma unroll 2
        for (int nn = 0; nn < 32; ++nn) {
            float4 e0 = *reinterpret_cast<const float4*>(&sE[nn][0]);
            float4 e1 = *reinterpret_cast<const float4*>(&sE[nn][4]);
            float4 e2 = *reinterpret_cast<const float4*>(&sE[nn][8]);
            float4 e3 = *reinterpret_cast<const float4*>(&sE[nn][12]);
            float en[EMB] = {e0.x,e0.y,e0.z,e0.w, e1.x,e1.y,e1.z,e1.w,
                             e2.x,e2.y,e2.z,e2.w, e3.x,e3.y,e3.z,e3.w};
            float a0 = 0.f, a1 = 0.f;
#pragma unroll
            for (int d = 0; d < EMB; ++d) {
                a0 += en[d] * w[0][d];
                a1 += en[d] * w[1][d];
            }
            unsigned int pk = (unsigned int)bfbits(a0) | ((unsigned int)bfbits(a1) << 16);
            __builtin_nontemporal_store(pk,
                reinterpret_cast<unsigned int*>(Wt + (size_t)(n0 + nn) * 12288 + oki0));
        }
    }
}

// ---------------------------------------------------------------------------
// C(4096x2048) = A @ Bt^T (both K=node contiguous, bf16).
// MODE 0: writes Cj (j-major) AND GT (node-major, scale 1)
// MODE 1: writes only GT (node-major, scale 2)
// ---------------------------------------------------------------------------
template<int MODE>
__global__ __launch_bounds__(256) void gemm_bt(
    const bf16_t* __restrict__ A, const bf16_t* __restrict__ Bt,
    bf16_t* __restrict__ Cj, bf16_t* __restrict__ GT) {
    __shared__ bf16_t smem[128 * TPAD];   // 35.3 KB; union of {As,Bs} and T
    bf16_t* As = smem;
    bf16_t* Bs = smem + 4096;
    bf16_t* T  = smem;
    const int tid  = threadIdx.x;
    const int wave = tid >> 6, lane = tid & 63;
    const int pBlk = blockIdx.x * 128;    // node cols
    const int mBlk = blockIdx.y * 128;    // j rows
    const int K = NN;

    const bf16_t* aSrc = A  + (size_t)(mBlk + wave * 32 + (lane >> 2)) * K + (lane & 3) * 8;
    const bf16_t* bSrc = Bt + (size_t)(pBlk + wave * 32 + (lane >> 2)) * K + (lane & 3) * 8;
    bf16_t* aDst = As + wave * 1024;
    bf16_t* bDst = Bs + wave * 1024;

    f32x4 acc[4][4] = {};
    const int wr = wave >> 1, wc = wave & 1;
    const int lrow = lane & 15, lk = (lane >> 4) * 8;

    for (int k0 = 0; k0 < K; k0 += 32) {
        GLOAD16(aSrc + k0,                  aDst);
        GLOAD16(aSrc + k0 + (size_t)16 * K, aDst + 512);
        GLOAD16(bSrc + k0,                  bDst);
        GLOAD16(bSrc + k0 + (size_t)16 * K, bDst + 512);
        __syncthreads();

        bf16x8 af[4], bb[4];
#pragma unroll
        for (int mf = 0; mf < 4; ++mf)
            af[mf] = *reinterpret_cast<const bf16x8*>(
                &As[(wr * 64 + mf * 16 + lrow) * 32 + lk]);
#pragma unroll
        for (int nf = 0; nf < 4; ++nf)
            bb[nf] = *reinterpret_cast<const bf16x8*>(
                &Bs[(wc * 64 + nf * 16 + lrow) * 32 + lk]);
#pragma unroll
        for (int mf = 0; mf < 4; ++mf)
#pragma unroll
            for (int nf = 0; nf < 4; ++nf)
                acc[mf][nf] = __builtin_amdgcn_mfma_f32_16x16x32_bf16(
                    af[mf], bb[nf], acc[mf][nf], 0, 0, 0);
        __syncthreads();
    }

    const int orow = (lane >> 4) * 4, ocol = lane & 15;
    if (MODE == 0) {
#pragma unroll
        for (int mf = 0; mf < 4; ++mf)
#pragma unroll
            for (int nf = 0; nf < 4; ++nf)
#pragma unroll
                for (int r = 0; r < 4; ++r) {
                    size_t row = (size_t)(mBlk + wr * 64 + mf * 16 + orow + r);
                    size_t col = (size_t)(pBlk + wc * 64 + nf * 16 + ocol);
                    Cj[row * NN + col] = (bf16_t)acc[mf][nf][r];
                }
    }
    const float scale = (MODE == 1) ? 2.f : 1.f;
#pragma unroll
    for (int mf = 0; mf < 4; ++mf)
#pragma unroll
        for (int nf = 0; nf < 4; ++nf)
#pragma unroll
            for (int r = 0; r < 4; ++r) {
                int trow = wr * 64 + mf * 16 + orow + r;   // local j
                int tcol = wc * 64 + nf * 16 + ocol;       // local n
                T[(size_t)tcol * TPAD + trow] = (bf16_t)(scale * acc[mf][nf][r]);
            }
    __syncthreads();
    {
        const int row = tid >> 1, half = tid & 1;
        const bf16_t* src = T + (size_t)row * TPAD + half * 64;
        bf16_t* dst = GT + (size_t)(pBlk + row) * JDIM + mBlk + half * 64;
#pragma unroll
        for (int s = 0; s < 8; ++s)
            *reinterpret_cast<uint4*>(dst + s * 8) =
                *reinterpret_cast<const uint4*>(src + s * 8);
    }
}

// ---------------------------------------------------------------------------
// Final grouped matmul, MFMA. One node per block (grid NN).
// Wt loads plain (L2 glues half-lines); out stores NT.
// ---------------------------------------------------------------------------
__global__ __launch_bounds__(256) void gconv_kernel(
    const float* __restrict__ x,   const float* __restrict__ E,
    const float* __restrict__ bp,  const bf16_t* __restrict__ G1T,
    const bf16_t* __restrict__ G2T, const bf16_t* __restrict__ Wt,
    float* __restrict__ out) {
    __shared__ bf16_t g[64][200];          // 25.6 KB
    const int n = blockIdx.x;
    const int tid = threadIdx.x, wave = tid >> 6, lane = tid & 63;
    const int lrow = lane & 15, lk = (lane >> 4) * 8;
    const int o = wave * 16 + lrow;        // this lane's output col

    // ---- prefetch Wt fragments + bias (independent of LDS) ----
    const bf16_t* wtn = Wt + (size_t)n * 12288 + (size_t)o * WKI;
    bf16x8 bb[6];
#pragma unroll
    for (int ks = 0; ks < 6; ++ks)
        bb[ks] = *reinterpret_cast<const bf16x8*>(wtn + ks * 32 + lk);
    float bo = 0.f;
    {
        const float* en = E + (size_t)n * EMB;
#pragma unroll
        for (int d = 0; d < EMB; ++d) bo += en[d] * bp[d * COUT + o];
    }

    // ---- stage g (cooperative) ----
#pragma unroll
    for (int p = 0; p < 2; ++p) {
        int idx = p * 256 + tid;                 // 0..511
        int b = idx >> 3, ic = (idx & 7) * 8;
        const float4* xs = reinterpret_cast<const float4*>(
            x + ((size_t)b * NN + n) * CIN + ic);
        float4 x0 = xs[0], x1 = xs[1];
        uint4 g1v = *reinterpret_cast<const uint4*>(G1T + (size_t)n * JDIM + idx * 8);
        uint4 g2v = *reinterpret_cast<const uint4*>(G2T + (size_t)n * JDIM + idx * 8);
        float xv[8] = {x0.x, x0.y, x0.z, x0.w, x1.x, x1.y, x1.z, x1.w};
        const bf16_t* g2p = reinterpret_cast<const bf16_t*>(&g2v);
        ushort4 g0b[2], g2b[2];
#pragma unroll
        for (int e = 0; e < 8; ++e) {
            ((unsigned short*)g0b)[e] = bfbits(xv[e]);
            ((unsigned short*)g2b)[e] = bfbits((float)g2p[e] - xv[e]);
        }
        *reinterpret_cast<uint4*>(&g[b][ic])       = *reinterpret_cast<uint4*>(g0b);
        *reinterpret_cast<uint4*>(&g[b][64 + ic])  = g1v;
        *reinterpret_cast<uint4*>(&g[b][128 + ic]) = *reinterpret_cast<uint4*>(g2b);
    }
    __syncthreads();

    // ---- compute: 64x16 output slice per wave, K=192 ----
    f32x4 acc[4] = {};
#pragma unroll
    for (int ks = 0; ks < 6; ++ks)
#pragma unroll
        for (int mf = 0; mf < 4; ++mf) {
            bf16x8 af = *reinterpret_cast<const bf16x8*>(&g[mf * 16 + lrow][ks * 32 + lk]);
            acc[mf] = __builtin_amdgcn_mfma_f32_16x16x32_bf16(af, bb[ks], acc[mf], 0, 0, 0);
        }
#pragma unroll
    for (int mf = 0; mf < 4; ++mf)
#pragma unroll
        for (int r = 0; r < 4; ++r) {
            int b = mf * 16 + (lane >> 4) * 4 + r;
            __builtin_nontemporal_store(acc[mf][r] + bo,
                &out[((size_t)b * NN + n) * COUT + o]);
        }
}

// ---------------------------------------------------------------------------
extern "C" void kernel_launch(void* const* d_in, const int* in_sizes, int n_in,
                              void* d_out, int out_size, void* d_ws, size_t ws_size,
                              hipStream_t stream) {
    const float* x  = (const float*)d_in[0];   // (64,2048,64)
    const float* E  = (const float*)d_in[1];   // (2048,16)
    const float* wp = (const float*)d_in[2];   // (16,3,64,64)
    const float* bp = (const float*)d_in[3];   // (16,64)
    float* out = (float*)d_out;

    bf16_t* ws = (bf16_t*)d_ws;
    bf16_t* Wt  = ws;                          // 2048*12288      = 48 MB
    bf16_t* Sb  = Wt + (size_t)NN * 12288;     // 2048*2048       =  8 MB
    bf16_t* Y0  = Sb + (size_t)NN * NN;        // 4096*2048       = 16 MB
    bf16_t* Y1  = Y0 + (size_t)JDIM * NN;      // 16 MB
    bf16_t* G1T = Y1 + (size_t)JDIM * NN;      // 16 MB  (total 104 MB)
    bf16_t* G2T = Y0;                          // alias: Y0 dead after gemm0

    // support (2048) + y0 (2048) + wgen (1536) fused, all independent
    prelude_kernel<<<5632, 256, 0, stream>>>(x, E, wp, Y0, Sb, Wt);

    dim3 ggrid(NN / 128, JDIM / 128);          // 16 x 32 = 512 blocks
    gemm_bt<0><<<ggrid, 256, 0, stream>>>(Y0, Sb, Y1, G1T);
    gemm_bt<1><<<ggrid, 256, 0, stream>>>(Y1, Sb, nullptr, G2T);

    gconv_kernel<<<NN, 256, 0, stream>>>(x, E, bp, G1T, G2T, Wt, out);
}